// Round 5
// baseline (501.196 us; speedup 1.0000x reference)
//
#include <hip/hip_runtime.h>
#include <hip/hip_bf16.h>

#define E_     8
#define C_     1024
#define H_     4096
#define N_TOK  4096
#define TOPK   2
#define NSLOT  (N_TOK*TOPK)   // 8192
#define SPAD   (NSLOT+256)    // padded rows for 256-row tile-tail reads

#define LPAD 40               // slow-path LDS row stride

typedef __attribute__((ext_vector_type(4))) float f32x4;
typedef __attribute__((ext_vector_type(8))) short short8;

__device__ __forceinline__ unsigned short f2bf(float f) {
    return __builtin_bit_cast(unsigned short, __float2bfloat16(f));
}

__device__ __forceinline__ void gload16(const void* g, const void* l) {
    __builtin_amdgcn_global_load_lds(
        (const __attribute__((address_space(1))) unsigned int*)g,
        (__attribute__((address_space(3))) unsigned int*)l, 16, 0, 0);
}

#define WAITVM_(n) asm volatile("s_waitcnt vmcnt(" #n ")" ::: "memory")
#define WAITVM(n) WAITVM_(n)
#define SWZ(r) ((((r)&3) ^ (((r)>>2)&3)))

// ---------------- router: 1 wave per token (no atomics) ----------------
__global__ void router_kernel(const float* __restrict__ x, const float* __restrict__ Wg,
                              int* __restrict__ sel, float* __restrict__ wts) {
    int wave = (blockIdx.x * blockDim.x + threadIdx.x) >> 6;
    int lane = threadIdx.x & 63;
    if (wave >= N_TOK) return;
    const float* xr = x + (size_t)wave * C_;
    float acc[E_];
#pragma unroll
    for (int e = 0; e < E_; ++e) acc[e] = 0.f;
    for (int c = lane; c < C_; c += 64) {
        float xv = xr[c];
#pragma unroll
        for (int e = 0; e < E_; ++e) acc[e] += xv * Wg[e * C_ + c];
    }
#pragma unroll
    for (int e = 0; e < E_; ++e) {
#pragma unroll
        for (int off = 32; off > 0; off >>= 1) acc[e] += __shfl_xor(acc[e], off);
    }
    if (lane == 0) {
        float mx = acc[0];
#pragma unroll
        for (int e = 1; e < E_; ++e) mx = fmaxf(mx, acc[e]);
        float p[E_]; float s = 0.f;
#pragma unroll
        for (int e = 0; e < E_; ++e) { p[e] = __expf(acc[e] - mx); s += p[e]; }
        float inv = 1.f / s;
#pragma unroll
        for (int e = 0; e < E_; ++e) p[e] *= inv;
        int b0 = 0; float v0 = p[0];
#pragma unroll
        for (int e = 1; e < E_; ++e) if (p[e] > v0) { v0 = p[e]; b0 = e; }
        int b1 = -1; float v1 = -1.f;
#pragma unroll
        for (int e = 0; e < E_; ++e) { if (e != b0 && p[e] > v1) { v1 = p[e]; b1 = e; } }
        float isum = 1.f / (v0 + v1);
        sel[wave*2]   = b0; sel[wave*2+1] = b1;
        wts[wave*2]   = v0 * isum; wts[wave*2+1] = v1 * isum;
    }
}

// ---------------- assign: deterministic positions, single block ----------------
__global__ void assign_kernel(const int* __restrict__ sel, const float* __restrict__ wts,
                              int* __restrict__ counts, int* __restrict__ offsets,
                              int* __restrict__ pos_of_slot, int* __restrict__ token_of,
                              float* __restrict__ slotw) {
    __shared__ int cnt[256][E_];
    __shared__ int offs[E_];
    int t = threadIdx.x;
    const int PER = NSLOT / 256;   // 32
    int base = t * PER;
    int loc[E_];
#pragma unroll
    for (int e = 0; e < E_; ++e) loc[e] = 0;
    for (int i = 0; i < PER; ++i) loc[sel[base + i]]++;
#pragma unroll
    for (int e = 0; e < E_; ++e) cnt[t][e] = loc[e];
    __syncthreads();
    if (t < E_) {
        int run = 0;
        for (int i = 0; i < 256; ++i) { int c = cnt[i][t]; cnt[i][t] = run; run += c; }
        counts[t] = run;
    }
    __syncthreads();
    if (t == 0) {
        int s = 0;
        for (int e = 0; e < E_; ++e) { offs[e] = s; offsets[e] = s; s += counts[e]; }
    }
    __syncthreads();
    int run[E_];
#pragma unroll
    for (int e = 0; e < E_; ++e) run[e] = offs[e] + cnt[t][e];
    for (int i = 0; i < PER; ++i) {
        int s = base + i;
        int e = sel[s];
        int p = run[e]++;
        pos_of_slot[s] = p;
        token_of[p] = s >> 1;
        slotw[p] = wts[s];
    }
}

// ---------------- copy: gather token rows to bf16 ----------------
__global__ void copy_kernel(const float* __restrict__ x, const int* __restrict__ pos_of_slot,
                            unsigned short* __restrict__ Xg) {
    int slot = blockIdx.x * 4 + (threadIdx.x >> 6);
    int lane = threadIdx.x & 63;
    int pos = pos_of_slot[slot];
    int n = slot >> 1;
    const float* xr = x + (size_t)n * C_;
    unsigned short* dst = Xg + (size_t)pos * C_;
#pragma unroll
    for (int i = 0; i < 4; ++i) {
        int c0 = i * 256 + lane * 4;
        float4 v = *(const float4*)(xr + c0);
        ushort4 b;
        b.x = f2bf(v.x); b.y = f2bf(v.y); b.z = f2bf(v.z); b.w = f2bf(v.w);
        *(ushort4*)(dst + c0) = b;
    }
}

// ---------------- wconv: per-expert transpose fp32 [R][Cc] -> bf16 [Cc][R] ----------------
__global__ void wconv_kernel(const float* __restrict__ src, unsigned short* __restrict__ dst,
                             int R, int Cc) {
    int e = blockIdx.z;
    int c0 = blockIdx.x * 64;
    int r0 = blockIdx.y * 64;
    const float* s = src + (size_t)e * R * Cc;
    unsigned short* d = dst + (size_t)e * R * Cc;
    __shared__ unsigned short t_[64][72];
    int t = threadIdx.x;
    int tr = t >> 4, tc4 = (t & 15) * 4;
#pragma unroll
    for (int i = 0; i < 4; ++i) {
        int r = tr + i * 16;
        float4 v = *(const float4*)(s + (size_t)(r0 + r) * Cc + c0 + tc4);
        t_[r][tc4+0] = f2bf(v.x); t_[r][tc4+1] = f2bf(v.y);
        t_[r][tc4+2] = f2bf(v.z); t_[r][tc4+3] = f2bf(v.w);
    }
    __syncthreads();
    int oc = t >> 2, seg = (t & 3) * 16;
    short8 w0, w1;
#pragma unroll
    for (int j = 0; j < 8; ++j) {
        w0[j] = (short)t_[seg + j][oc];
        w1[j] = (short)t_[seg + 8 + j][oc];
    }
    unsigned short* dp = d + (size_t)(c0 + oc) * R + r0 + seg;
    *(short8*)dp = w0;
    *(short8*)(dp + 8) = w1;
}

// ============ ring GEMMs: 256x128 tile, K-half(32) ring of 4 slots, 8 waves ============
// Per phase (one K-half): ds_read 12 frags (a reused for b1,b3) -> issue staging of half
// h+3 (4 gloads) -> WAITVM(8) (retires half h+1, 2-phase slack) -> MFMA x32 -> 1 barrier.
// Swizzle: 64B rows of 4x16B chunks, phys = logical ^ ((row&3)^((row>>2)&3)), applied on
// global source AND ds_read (involution); gload_lds dest stays linear -> 2-way (free).

#define G1_NH (C_/32)    // 32 halves

__global__ __launch_bounds__(512, 2) void gemm1_ring(
        const unsigned short* __restrict__ Xg, const unsigned short* __restrict__ W1t,
        const unsigned short* __restrict__ W3t, unsigned short* __restrict__ G,
        const int* __restrict__ counts, const int* __restrict__ offsets) {
    int ct = blockIdx.x;            // H/128 = 32 col tiles
    int rslot = blockIdx.y;         // e*32 + rt
    int e = rslot >> 5, rt = rslot & 31;
    int ne = counts[e];
    if (rt * 256 >= ne) return;
    int row0 = offsets[e] + rt * 256;
    int n0 = ct * 128;

    extern __shared__ char lds[];
    char* As  = lds;            // 4 slots x 16384 B (256 rows x 64B)
    char* B1s = lds + 65536;    // 4 slots x 8192 B (128 rows x 64B)
    char* B3s = lds + 98304;    // 4 slots x 8192 B

    int tid = threadIdx.x, lane = tid & 63, wid = tid >> 6;
    int wm = wid >> 1, wn = wid & 1;
    int fr = lane & 15, q = lane >> 4;
    int srow = lane >> 2, pchk = lane & 3;

    const unsigned short* Ap  = Xg + (size_t)row0 * C_;
    const unsigned short* B1p = W1t + ((size_t)e * H_ + n0) * C_;
    const unsigned short* B3p = W3t + ((size_t)e * H_ + n0) * C_;

    f32x4 acc1[4][4], acc3[4][4];
#pragma unroll
    for (int m = 0; m < 4; ++m)
#pragma unroll
        for (int n = 0; n < 4; ++n) {
            acc1[m][n] = (f32x4){0.f,0.f,0.f,0.f};
            acc3[m][n] = (f32x4){0.f,0.f,0.f,0.f};
        }

    auto STAGE = [&](int hs, int slot) {
        int k0 = hs * 32;
#pragma unroll
        for (int r = 0; r < 2; ++r) {
            int row = r*128 + wid*16 + srow;
            int sc = pchk ^ SWZ(row);
            gload16(Ap + (size_t)row * C_ + k0 + sc*8,
                    As + slot*16384 + (r*128 + wid*16)*64);
        }
        {
            int row = wid*16 + srow;
            int sc = pchk ^ SWZ(row);
            gload16(B1p + (size_t)row * C_ + k0 + sc*8, B1s + slot*8192 + wid*1024);
            gload16(B3p + (size_t)row * C_ + k0 + sc*8, B3s + slot*8192 + wid*1024);
        }
    };

    STAGE(0, 0); STAGE(1, 1); STAGE(2, 2);   // 12 loads in flight
    WAITVM(8);                               // half 0 landed
    __builtin_amdgcn_s_barrier();

    for (int h = 0; h < G1_NH; ++h) {
        int slot = h & 3;
        short8 a[4], b1[4], b3[4];
#pragma unroll
        for (int m = 0; m < 4; ++m) {
            int row = wm*64 + m*16 + fr;
            a[m] = *(const short8*)(As + slot*16384 + row*64 + ((q ^ SWZ(row)) << 4));
        }
#pragma unroll
        for (int n = 0; n < 4; ++n) {
            int row = wn*64 + n*16 + fr;
            int so = row*64 + ((q ^ SWZ(row)) << 4);
            b1[n] = *(const short8*)(B1s + slot*8192 + so);
            b3[n] = *(const short8*)(B3s + slot*8192 + so);
        }
        int hs = (h + 3 < G1_NH) ? h + 3 : G1_NH - 1;   // tail: dummy re-stage (ledger invariant)
        STAGE(hs, (h + 3) & 3);
        WAITVM(8);                           // retires half h+1
        __builtin_amdgcn_sched_barrier(0);
        __builtin_amdgcn_s_setprio(1);
#pragma unroll
        for (int m = 0; m < 4; ++m)
#pragma unroll
            for (int n = 0; n < 4; ++n) {
                acc1[m][n] = __builtin_amdgcn_mfma_f32_16x16x32_bf16(a[m], b1[n], acc1[m][n], 0, 0, 0);
                acc3[m][n] = __builtin_amdgcn_mfma_f32_16x16x32_bf16(a[m], b3[n], acc3[m][n], 0, 0, 0);
            }
        __builtin_amdgcn_s_setprio(0);
        __builtin_amdgcn_s_barrier();
    }
    WAITVM(0);   // drain dummy staging before kernel end

    // epilogue: silu(h1)*h3 -> bf16 G
#pragma unroll
    for (int m = 0; m < 4; ++m)
#pragma unroll
        for (int rg = 0; rg < 4; ++rg) {
            int row = wm*64 + m*16 + q*4 + rg;
            if (rt * 256 + row < ne) {
                size_t gbase = (size_t)(row0 + row) * H_ + n0 + wn*64;
#pragma unroll
                for (int n = 0; n < 4; ++n) {
                    float h1 = acc1[m][n][rg];
                    float h3 = acc3[m][n][rg];
                    float g = h1 * h3 / (1.f + __expf(-h1));
                    G[gbase + n*16 + fr] = f2bf(g);
                }
            }
        }
}

#define G2_NH (H_/32)    // 128 halves

__global__ __launch_bounds__(512, 2) void gemm2_ring(
        const unsigned short* __restrict__ G, const unsigned short* __restrict__ W2t,
        float* __restrict__ out, const int* __restrict__ counts,
        const int* __restrict__ offsets, const int* __restrict__ token_of,
        const float* __restrict__ slotw) {
    int ct = blockIdx.x;            // C/128 = 8 col tiles
    int rslot = blockIdx.y;
    int e = rslot >> 5, rt = rslot & 31;
    int ne = counts[e];
    if (rt * 256 >= ne) return;
    int row0 = offsets[e] + rt * 256;
    int n0 = ct * 128;

    extern __shared__ char lds[];
    char* As = lds;             // 4 slots x 16384 B
    char* Bs = lds + 65536;     // 4 slots x 8192 B

    int tid = threadIdx.x, lane = tid & 63, wid = tid >> 6;
    int wm = wid >> 1, wn = wid & 1;
    int fr = lane & 15, q = lane >> 4;
    int srow = lane >> 2, pchk = lane & 3;

    const unsigned short* Ap = G + (size_t)row0 * H_;
    const unsigned short* Bp = W2t + ((size_t)e * C_ + n0) * H_;

    f32x4 acc[4][4];
#pragma unroll
    for (int m = 0; m < 4; ++m)
#pragma unroll
        for (int n = 0; n < 4; ++n) acc[m][n] = (f32x4){0.f,0.f,0.f,0.f};

    auto STAGE = [&](int hs, int slot) {
        int k0 = hs * 32;
#pragma unroll
        for (int r = 0; r < 2; ++r) {
            int row = r*128 + wid*16 + srow;
            int sc = pchk ^ SWZ(row);
            gload16(Ap + (size_t)row * H_ + k0 + sc*8,
                    As + slot*16384 + (r*128 + wid*16)*64);
        }
        {
            int row = wid*16 + srow;
            int sc = pchk ^ SWZ(row);
            gload16(Bp + (size_t)row * H_ + k0 + sc*8, Bs + slot*8192 + wid*1024);
        }
    };

    STAGE(0, 0); STAGE(1, 1); STAGE(2, 2);   // 9 loads in flight
    WAITVM(6);                               // half 0 landed
    __builtin_amdgcn_s_barrier();

    for (int h = 0; h < G2_NH; ++h) {
        int slot = h & 3;
        short8 a[4], b[4];
#pragma unroll
        for (int m = 0; m < 4; ++m) {
            int row = wm*64 + m*16 + fr;
            a[m] = *(const short8*)(As + slot*16384 + row*64 + ((q ^ SWZ(row)) << 4));
        }
#pragma unroll
        for (int n = 0; n < 4; ++n) {
            int row = wn*64 + n*16 + fr;
            b[n] = *(const short8*)(Bs + slot*8192 + row*64 + ((q ^ SWZ(row)) << 4));
        }
        int hs = (h + 3 < G2_NH) ? h + 3 : G2_NH - 1;
        STAGE(hs, (h + 3) & 3);
        WAITVM(6);                           // retires half h+1
        __builtin_amdgcn_sched_barrier(0);
        __builtin_amdgcn_s_setprio(1);
#pragma unroll
        for (int m = 0; m < 4; ++m)
#pragma unroll
            for (int n = 0; n < 4; ++n)
                acc[m][n] = __builtin_amdgcn_mfma_f32_16x16x32_bf16(a[m], b[n], acc[m][n], 0, 0, 0);
        __builtin_amdgcn_s_setprio(0);
        __builtin_amdgcn_s_barrier();
    }
    WAITVM(0);

    // epilogue: scatter-add weighted partial into out
#pragma unroll
    for (int m = 0; m < 4; ++m)
#pragma unroll
        for (int rg = 0; rg < 4; ++rg) {
            int row = wm*64 + m*16 + q*4 + rg;
            if (rt * 256 + row < ne) {
                int grow = row0 + row;
                int tok = token_of[grow];
                float w = slotw[grow];
                float* orow = out + (size_t)tok * C_ + n0 + wn*64;
#pragma unroll
                for (int n = 0; n < 4; ++n)
                    atomicAdd(orow + n*16 + fr, acc[m][n][rg] * w);
            }
        }
}

// ============ SLOW PATH (fallback if ws too small) ============
#define BM 128
#define BN 128
#define BK 32
__global__ __launch_bounds__(256, 2) void gemm1_slow(
        const unsigned short* __restrict__ Xg, const float* __restrict__ W1,
        const float* __restrict__ W3, unsigned short* __restrict__ G,
        const int* __restrict__ counts, const int* __restrict__ offsets) {
    int ct = blockIdx.x;
    int rslot = blockIdx.y;
    int e = rslot >> 5, rt = rslot & 31;
    int ne = counts[e];
    if (rt * BM >= ne) return;
    int row0 = offsets[e] + rt * BM;
    int n0 = ct * BN;

    __shared__ unsigned short As[BM][LPAD];
    __shared__ unsigned short B1s[BN][LPAD];
    __shared__ unsigned short B3s[BN][LPAD];

    int tid = threadIdx.x;
    int lane = tid & 63, wid = tid >> 6;
    int wr = (wid >> 1) * 64, wc = (wid & 1) * 64;

    f32x4 acc1[4][4], acc3[4][4];
#pragma unroll
    for (int m = 0; m < 4; ++m)
#pragma unroll
        for (int n = 0; n < 4; ++n) {
            acc1[m][n] = (f32x4){0.f,0.f,0.f,0.f};
            acc3[m][n] = (f32x4){0.f,0.f,0.f,0.f};
        }

    const float* B1p = W1 + (size_t)e * C_ * H_ + n0;
    const float* B3p = W3 + (size_t)e * C_ * H_ + n0;
    int chunk = tid & 3, rr = tid >> 2;
    int kq = tid >> 5, n4 = tid & 31;

    for (int k0 = 0; k0 < C_; k0 += BK) {
        __syncthreads();
#pragma unroll
        for (int h = 0; h < 2; ++h) {
            int row = rr + h * 64;
            uint4 v = *(const uint4*)(Xg + (size_t)(row0 + row) * C_ + k0 + chunk * 8);
            *(uint4*)&As[row][chunk * 8] = v;
        }
        {
            float4 r0 = *(const float4*)(B1p + (size_t)(k0 + kq*4 + 0) * H_ + n4*4);
            float4 r1 = *(const float4*)(B1p + (size_t)(k0 + kq*4 + 1) * H_ + n4*4);
            float4 r2 = *(const float4*)(B1p + (size_t)(k0 + kq*4 + 2) * H_ + n4*4);
            float4 r3 = *(const float4*)(B1p + (size_t)(k0 + kq*4 + 3) * H_ + n4*4);
            ushort4 w0 = {f2bf(r0.x), f2bf(r1.x), f2bf(r2.x), f2bf(r3.x)};
            ushort4 w1 = {f2bf(r0.y), f2bf(r1.y), f2bf(r2.y), f2bf(r3.y)};
            ushort4 w2 = {f2bf(r0.z), f2bf(r1.z), f2bf(r2.z), f2bf(r3.z)};
            ushort4 w3 = {f2bf(r0.w), f2bf(r1.w), f2bf(r2.w), f2bf(r3.w)};
            *(ushort4*)&B1s[n4*4+0][kq*4] = w0;
            *(ushort4*)&B1s[n4*4+1][kq*4] = w1;
            *(ushort4*)&B1s[n4*4+2][kq*4] = w2;
            *(ushort4*)&B1s[n4*4+3][kq*4] = w3;
            r0 = *(const float4*)(B3p + (size_t)(k0 + kq*4 + 0) * H_ + n4*4);
            r1 = *(const float4*)(B3p + (size_t)(k0 + kq*4 + 1) * H_ + n4*4);
            r2 = *(const float4*)(B3p + (size_t)(k0 + kq*4 + 2) * H_ + n4*4);
            r3 = *(const float4*)(B3p + (size_t)(k0 + kq*4 + 3) * H_ + n4*4);
            w0 = (ushort4){f2bf(r0.x), f2bf(r1.x), f2bf(r2.x), f2bf(r3.x)};
            w1 = (ushort4){f2bf(r0.y), f2bf(r1.y), f2bf(r2.y), f2bf(r3.y)};
            w2 = (ushort4){f2bf(r0.z), f2bf(r1.z), f2bf(r2.z), f2bf(r3.z)};
            w3 = (ushort4){f2bf(r0.w), f2bf(r1.w), f2bf(r2.w), f2bf(r3.w)};
            *(ushort4*)&B3s[n4*4+0][kq*4] = w0;
            *(ushort4*)&B3s[n4*4+1][kq*4] = w1;
            *(ushort4*)&B3s[n4*4+2][kq*4] = w2;
            *(ushort4*)&B3s[n4*4+3][kq*4] = w3;
        }
        __syncthreads();
        int q = lane >> 4, fr = lane & 15;
        short8 a[4], b1[4], b3[4];
#pragma unroll
        for (int m = 0; m < 4; ++m) a[m] = *(const short8*)&As[wr + m*16 + fr][q*8];
#pragma unroll
        for (int n = 0; n < 4; ++n) {
            b1[n] = *(const short8*)&B1s[wc + n*16 + fr][q*8];
            b3[n] = *(const short8*)&B3s[wc + n*16 + fr][q*8];
        }
#pragma unroll
        for (int m = 0; m < 4; ++m)
#pragma unroll
            for (int n = 0; n < 4; ++n) {
                acc1[m][n] = __builtin_amdgcn_mfma_f32_16x16x32_bf16(a[m], b1[n], acc1[m][n], 0, 0, 0);
                acc3[m][n] = __builtin_amdgcn_mfma_f32_16x16x32_bf16(a[m], b3[n], acc3[m][n], 0, 0, 0);
            }
    }
    int q = lane >> 4, cfr = lane & 15;
#pragma unroll
    for (int m = 0; m < 4; ++m) {
#pragma unroll
        for (int rg = 0; rg < 4; ++rg) {
            int row = wr + m*16 + q*4 + rg;
            if (rt * BM + row < ne) {
                size_t gbase = (size_t)(row0 + row) * H_ + n0;
#pragma unroll
                for (int n = 0; n < 4; ++n) {
                    float h1 = acc1[m][n][rg];
                    float h3 = acc3[m][n][rg];
                    float g = h1 * h3 / (1.f + __expf(-h1));
                    G[gbase + wc + n*16 + cfr] = f2bf(g);
                }
            }
        }
    }
}

__global__ __launch_bounds__(256, 2) void gemm2_slow(
        const unsigned short* __restrict__ G, const float* __restrict__ W2,
        float* __restrict__ out, const int* __restrict__ counts,
        const int* __restrict__ offsets, const int* __restrict__ token_of,
        const float* __restrict__ slotw) {
    int ct = blockIdx.x;
    int rslot = blockIdx.y;
    int e = rslot >> 5, rt = rslot & 31;
    int ne = counts[e];
    if (rt * BM >= ne) return;
    int row0 = offsets[e] + rt * BM;
    int n0 = ct * BN;

    __shared__ unsigned short As[BM][LPAD];
    __shared__ unsigned short Bs[BN][LPAD];

    int tid = threadIdx.x;
    int lane = tid & 63, wid = tid >> 6;
    int wr = (wid >> 1) * 64, wc = (wid & 1) * 64;

    f32x4 acc[4][4];
#pragma unroll
    for (int m = 0; m < 4; ++m)
#pragma unroll
        for (int n = 0; n < 4; ++n) acc[m][n] = (f32x4){0.f,0.f,0.f,0.f};

    const float* Bp = W2 + (size_t)e * H_ * C_ + n0;
    int chunk = tid & 3, rr = tid >> 2;
    int kq = tid >> 5, n4 = tid & 31;

    for (int k0 = 0; k0 < H_; k0 += BK) {
        __syncthreads();
#pragma unroll
        for (int h = 0; h < 2; ++h) {
            int row = rr + h * 64;
            uint4 v = *(const uint4*)(G + (size_t)(row0 + row) * H_ + k0 + chunk * 8);
            *(uint4*)&As[row][chunk * 8] = v;
        }
        {
            float4 r0 = *(const float4*)(Bp + (size_t)(k0 + kq*4 + 0) * C_ + n4*4);
            float4 r1 = *(const float4*)(Bp + (size_t)(k0 + kq*4 + 1) * C_ + n4*4);
            float4 r2 = *(const float4*)(Bp + (size_t)(k0 + kq*4 + 2) * C_ + n4*4);
            float4 r3 = *(const float4*)(Bp + (size_t)(k0 + kq*4 + 3) * C_ + n4*4);
            ushort4 w0 = {f2bf(r0.x), f2bf(r1.x), f2bf(r2.x), f2bf(r3.x)};
            ushort4 w1 = {f2bf(r0.y), f2bf(r1.y), f2bf(r2.y), f2bf(r3.y)};
            ushort4 w2 = {f2bf(r0.z), f2bf(r1.z), f2bf(r2.z), f2bf(r3.z)};
            ushort4 w3 = {f2bf(r0.w), f2bf(r1.w), f2bf(r2.w), f2bf(r3.w)};
            *(ushort4*)&Bs[n4*4+0][kq*4] = w0;
            *(ushort4*)&Bs[n4*4+1][kq*4] = w1;
            *(ushort4*)&Bs[n4*4+2][kq*4] = w2;
            *(ushort4*)&Bs[n4*4+3][kq*4] = w3;
        }
        __syncthreads();
        int q = lane >> 4, fr = lane & 15;
        short8 a[4], b[4];
#pragma unroll
        for (int m = 0; m < 4; ++m) a[m] = *(const short8*)&As[wr + m*16 + fr][q*8];
#pragma unroll
        for (int n = 0; n < 4; ++n) b[n] = *(const short8*)&Bs[wc + n*16 + fr][q*8];
#pragma unroll
        for (int m = 0; m < 4; ++m)
#pragma unroll
            for (int n = 0; n < 4; ++n)
                acc[m][n] = __builtin_amdgcn_mfma_f32_16x16x32_bf16(a[m], b[n], acc[m][n], 0, 0, 0);
    }
    int q = lane >> 4, cfr = lane & 15;
#pragma unroll
    for (int m = 0; m < 4; ++m) {
#pragma unroll
        for (int rg = 0; rg < 4; ++rg) {
            int row = wr + m*16 + q*4 + rg;
            if (rt * BM + row < ne) {
                int grow = row0 + row;
                int tok = token_of[grow];
                float w = slotw[grow];
                float* orow = out + (size_t)tok * C_ + n0;
#pragma unroll
                for (int n = 0; n < 4; ++n)
                    atomicAdd(orow + wc + n*16 + cfr, acc[m][n][rg] * w);
            }
        }
    }
}

extern "C" void kernel_launch(void* const* d_in, const int* in_sizes, int n_in,
                              void* d_out, int out_size, void* d_ws, size_t ws_size,
                              hipStream_t stream) {
    const float* x  = (const float*)d_in[0];
    const float* Wg = (const float*)d_in[1];
    const float* W1 = (const float*)d_in[2];
    const float* W2 = (const float*)d_in[3];
    const float* W3 = (const float*)d_in[4];
    float* out = (float*)d_out;

    char* ws = (char*)d_ws;
    size_t o = 0;
    int*   sel      = (int*)(ws + o);  o += (size_t)NSLOT * 4;
    float* wts      = (float*)(ws + o); o += (size_t)NSLOT * 4;
    int*   pos      = (int*)(ws + o);  o += (size_t)NSLOT * 4;
    int*   token_of = (int*)(ws + o);  o += (size_t)NSLOT * 4;
    float* slotw    = (float*)(ws + o); o += (size_t)NSLOT * 4;
    int*   counts   = (int*)(ws + o);
    int*   offsets  = counts + E_;     o += 256;
    unsigned short* Xg = (unsigned short*)(ws + o); o += (size_t)SPAD * C_ * 2;
    unsigned short* G  = (unsigned short*)(ws + o); o += (size_t)SPAD * H_ * 2;
    size_t need_slow = o;
    unsigned short* W1t = (unsigned short*)(ws + o); o += (size_t)E_ * H_ * C_ * 2;
    unsigned short* W3t = (unsigned short*)(ws + o); o += (size_t)E_ * H_ * C_ * 2;
    unsigned short* W2t = W1t;   // W1t region freed after gemm1
    size_t need_fast = o;

    hipMemsetAsync(d_out, 0, (size_t)out_size * sizeof(float), stream);
    if (ws_size < need_slow) return;

    router_kernel<<<N_TOK/4, 256, 0, stream>>>(x, Wg, sel, wts);
    assign_kernel<<<1, 256, 0, stream>>>(sel, wts, counts, offsets, pos, token_of, slotw);
    copy_kernel<<<NSLOT/4, 256, 0, stream>>>(x, pos, Xg);

    if (ws_size >= need_fast) {
        hipFuncSetAttribute((const void*)gemm1_ring, hipFuncAttributeMaxDynamicSharedMemorySize, 131072);
        hipFuncSetAttribute((const void*)gemm2_ring, hipFuncAttributeMaxDynamicSharedMemorySize, 98304);
        wconv_kernel<<<dim3(H_/64, C_/64, E_), 256, 0, stream>>>(W1, W1t, C_, H_);
        wconv_kernel<<<dim3(H_/64, C_/64, E_), 256, 0, stream>>>(W3, W3t, C_, H_);
        gemm1_ring<<<dim3(H_/128, E_*32), 512, 131072, stream>>>(Xg, W1t, W3t, G, counts, offsets);
        wconv_kernel<<<dim3(C_/64, H_/64, E_), 256, 0, stream>>>(W2, W2t, H_, C_);
        gemm2_ring<<<dim3(C_/128, E_*32), 512, 98304, stream>>>(G, W2t, out, counts, offsets, token_of, slotw);
    } else {
        gemm1_slow<<<dim3(H_/BN, E_*32), 256, 0, stream>>>(Xg, W1, W3, G, counts, offsets);
        gemm2_slow<<<dim3(C_/BN, E_*32), 256, 0, stream>>>(G, W2, out, counts, offsets, token_of, slotw);
    }
}